// Round 5
// baseline (24.327 us; speedup 1.0000x reference)
//
#include <hip/hip_runtime.h>

// SimpleCNN forward, mathematically simplified (validated rounds 1-4):
//   out = fc( pool(relu(s*conv2+b2)( pool(relu(s*conv1+b1)(x)) )) ),  s = 1/(1+1e-5)
// Round 5: occupancy + conv2 re-tile.
//  - 512-thread blocks (1 sample/block) -> 16 waves/CU (4/SIMD), 2x latency hiding
//  - conv2 thread = (pool-row, oc-pair, cp-quarter): each patch b128 feeds 2 oc,
//    weights as ds_read_b64 (oc-pair adjacent, row stride 34 for 8B align),
//    cp-partials reduced with quad-local shfl_xor (no LDS, no barrier)
//  - sh1p cp-plane stride 264 u32 -> cross-cp reads 2-way/bank (free)

typedef __fp16 h2v __attribute__((ext_vector_type(2)));

__device__ __forceinline__ h2v as_h2(unsigned u) {
    union { unsigned u; h2v h; } x; x.u = u; return x.h;
}
__device__ __forceinline__ unsigned as_u32(h2v h) {
    union { unsigned u; h2v h; } x; x.h = h; return x.u;
}

__global__ __launch_bounds__(512, 4) void fused_cnn(
    const float* __restrict__ x,     // (512,1,28,28)
    const float* __restrict__ w1,    // (16,1,3,3)
    const float* __restrict__ b1,    // (16,)
    const float* __restrict__ w2,    // (32,16,3,3)
    const float* __restrict__ b2,    // (32,)
    const float* __restrict__ fcw,   // (10,1568)
    const float* __restrict__ fcb,   // (10,)
    float* __restrict__ out)         // (512,10)
{
    const int n = blockIdx.x;
    const int t = threadIdx.x;
    const float s = (float)(1.0 / 1.00001);   // 1/(1+TEMP)

    __shared__ float    sx[30 * 36];     // padded x, stride 36, real [1..28][1..28]
    __shared__ unsigned sh1p[8 * 264];   // [cp][16][16] half2, plane stride 264 u32
    __shared__ unsigned wpk[72 * 34];    // [(cp*9+k)*34 + oc] packed half2 of w2
    __shared__ float    sh2[1568];       // (32,7,7)
    __shared__ float    sred[10][8];

    // ---- stage ----
    for (int i = t; i < 1080; i += 512) sx[i] = 0.0f;
    for (int i = t; i < 2112; i += 512) sh1p[i] = 0u;
    if (t < 196) {
        const float4 v = ((const float4*)(x + n * 784))[t];
        const int r = t / 7, c4 = (t - r * 7) * 4;
        float* dst = &sx[(r + 1) * 36 + c4 + 1];
        dst[0] = v.x; dst[1] = v.y; dst[2] = v.z; dst[3] = v.w;
    }
    for (int i = t; i < 2304; i += 512) {
        const int oc = i / 72, r = i - oc * 72;
        const int cp = r / 9, k = r - cp * 9;
        const float a = w2[(oc * 16 + 2 * cp) * 9 + k];
        const float b = w2[(oc * 16 + 2 * cp + 1) * 9 + k];
        wpk[(cp * 9 + k) * 34 + oc] = as_u32(__builtin_amdgcn_cvt_pkrtz(a, b));
    }
    __syncthreads();

    // ---- conv1 + relu + pool -> sh1p ----
    // thread: ocp = t&7 (out-ch 2ocp,2ocp+1), positions p = t>>3, t>>3 + 64
    {
        const int ocp = t & 7;
        float wa[9], wb[9];
        #pragma unroll
        for (int k = 0; k < 9; ++k) { wa[k] = w1[ocp * 18 + k]; wb[k] = w1[ocp * 18 + 9 + k]; }
        const float ba = b1[2 * ocp], bb = b1[2 * ocp + 1];

        for (int p = t >> 3; p < 98; p += 64) {
            const int row = p / 7;
            const int pcp = p - row * 7;
            float pr[4][6];
            const float* base = &sx[(2 * row) * 36 + 4 * pcp];
            #pragma unroll
            for (int rr = 0; rr < 4; ++rr) {
                const float4 a4 = *(const float4*)(base + rr * 36);
                const float2 a2 = *(const float2*)(base + rr * 36 + 4);
                pr[rr][0] = a4.x; pr[rr][1] = a4.y; pr[rr][2] = a4.z; pr[rr][3] = a4.w;
                pr[rr][4] = a2.x; pr[rr][5] = a2.y;
            }
            float va[2][4], vb[2][4];
            #pragma unroll
            for (int cr = 0; cr < 2; ++cr)
                #pragma unroll
                for (int cc = 0; cc < 4; ++cc) {
                    float a = 0.0f, b = 0.0f;
                    #pragma unroll
                    for (int ki = 0; ki < 3; ++ki)
                        #pragma unroll
                        for (int kj = 0; kj < 3; ++kj) {
                            const float pv = pr[cr + ki][cc + kj];
                            a = fmaf(wa[ki * 3 + kj], pv, a);
                            b = fmaf(wb[ki * 3 + kj], pv, b);
                        }
                    va[cr][cc] = a; vb[cr][cc] = b;
                }
            #pragma unroll
            for (int d = 0; d < 2; ++d) {
                const float ma = fmaxf(fmaxf(va[0][2 * d], va[0][2 * d + 1]),
                                       fmaxf(va[1][2 * d], va[1][2 * d + 1]));
                const float mb = fmaxf(fmaxf(vb[0][2 * d], vb[0][2 * d + 1]),
                                       fmaxf(vb[1][2 * d], vb[1][2 * d + 1]));
                const float pa = fmaxf(fmaf(s, ma, ba), 0.0f);
                const float pb = fmaxf(fmaf(s, mb, bb), 0.0f);
                sh1p[ocp * 264 + (row + 1) * 16 + (1 + 2 * pcp + d)] =
                    as_u32(__builtin_amdgcn_cvt_pkrtz(pa, pb));
            }
        }
    }
    __syncthreads();

    // ---- conv2 (dot2, 2 oc x 2 cp per thread) + quad shfl-reduce + relu + pool ----
    // t = row*64 + ocp*4 + X : row 0..6, ocp 0..15 (oc 2ocp,2ocp+1), X = cp-quarter
    if (t < 448) {
        const int row = t >> 6;
        const int rem = t & 63;
        const int ocp = rem >> 2;
        const int X   = rem & 3;

        float acc0[2][14], acc1[2][14];
        #pragma unroll
        for (int cr = 0; cr < 2; ++cr)
            #pragma unroll
            for (int j = 0; j < 14; ++j) { acc0[cr][j] = 0.0f; acc1[cr][j] = 0.0f; }

        #pragma unroll
        for (int c2 = 0; c2 < 2; ++c2) {
            const int cp = 2 * X + c2;
            uint2 wq[9];
            const unsigned* wbase = &wpk[(cp * 9) * 34 + 2 * ocp];
            #pragma unroll
            for (int k = 0; k < 9; ++k) wq[k] = *(const uint2*)(wbase + k * 34);

            auto apply = [&](const unsigned* prow, int CR, int KI) {
                #pragma unroll
                for (int kj = 0; kj < 3; ++kj) {
                    const h2v w0 = as_h2(wq[KI * 3 + kj].x);
                    const h2v w1v = as_h2(wq[KI * 3 + kj].y);
                    #pragma unroll
                    for (int j = 0; j < 14; ++j) {
                        const h2v p = as_h2(prow[j + kj]);
                        acc0[CR][j] = __builtin_amdgcn_fdot2(p, w0, acc0[CR][j], false);
                        acc1[CR][j] = __builtin_amdgcn_fdot2(p, w1v, acc1[CR][j], false);
                    }
                }
            };

            #pragma unroll
            for (int rr = 0; rr < 4; ++rr) {
                unsigned prow[16];
                const unsigned* bp = &sh1p[cp * 264 + (2 * row + rr) * 16];
                #pragma unroll
                for (int q = 0; q < 4; ++q) {
                    const uint4 a = *(const uint4*)(bp + q * 4);
                    prow[q * 4 + 0] = a.x; prow[q * 4 + 1] = a.y;
                    prow[q * 4 + 2] = a.z; prow[q * 4 + 3] = a.w;
                }
                if (rr == 0)      { apply(prow, 0, 0); }
                else if (rr == 1) { apply(prow, 0, 1); apply(prow, 1, 0); }
                else if (rr == 2) { apply(prow, 0, 2); apply(prow, 1, 1); }
                else              { apply(prow, 1, 2); }
            }
        }

        // reduce partials over X (lanes t^1, t^2 within the quad)
        #pragma unroll
        for (int cr = 0; cr < 2; ++cr)
            #pragma unroll
            for (int j = 0; j < 14; ++j) {
                float v0 = acc0[cr][j];
                v0 += __shfl_xor(v0, 1); v0 += __shfl_xor(v0, 2);
                acc0[cr][j] = v0;
                float v1 = acc1[cr][j];
                v1 += __shfl_xor(v1, 1); v1 += __shfl_xor(v1, 2);
                acc1[cr][j] = v1;
            }

        if (X == 0) {
            const int oc0 = 2 * ocp, oc1 = 2 * ocp + 1;
            const float bb0 = b2[oc0], bb1 = b2[oc1];
            #pragma unroll
            for (int d = 0; d < 7; ++d) {
                const float m0 = fmaxf(fmaxf(acc0[0][2 * d], acc0[0][2 * d + 1]),
                                       fmaxf(acc0[1][2 * d], acc0[1][2 * d + 1]));
                const float m1 = fmaxf(fmaxf(acc1[0][2 * d], acc1[0][2 * d + 1]),
                                       fmaxf(acc1[1][2 * d], acc1[1][2 * d + 1]));
                sh2[oc0 * 49 + row * 7 + d] = fmaxf(fmaf(s, m0, bb0), 0.0f);
                sh2[oc1 * 49 + row * 7 + d] = fmaxf(fmaf(s, m1, bb1), 0.0f);
            }
        }
    }
    __syncthreads();

    // ---- fc (float4 vectorized) ----
    float part[10];
    #pragma unroll
    for (int j = 0; j < 10; ++j) part[j] = 0.0f;
    const float4* sh2v = (const float4*)sh2;
    const float4* fcwv = (const float4*)fcw;
    for (int i = t; i < 392; i += 512) {
        const float4 h = sh2v[i];
        #pragma unroll
        for (int j = 0; j < 10; ++j) {
            const float4 wq = fcwv[j * 392 + i];
            part[j] = fmaf(h.x, wq.x, fmaf(h.y, wq.y,
                      fmaf(h.z, wq.z, fmaf(h.w, wq.w, part[j]))));
        }
    }
    #pragma unroll
    for (int j = 0; j < 10; ++j) {
        float vsum = part[j];
        #pragma unroll
        for (int off = 32; off > 0; off >>= 1) vsum += __shfl_down(vsum, off);
        if ((t & 63) == 0) sred[j][t >> 6] = vsum;
    }
    __syncthreads();
    if (t < 10) {
        float v = fcb[t];
        #pragma unroll
        for (int w = 0; w < 8; ++w) v += sred[t][w];
        out[n * 10 + t] = v;
    }
}

extern "C" void kernel_launch(void* const* d_in, const int* in_sizes, int n_in,
                              void* d_out, int out_size, void* d_ws, size_t ws_size,
                              hipStream_t stream) {
    const float* x   = (const float*)d_in[0];
    const float* w1  = (const float*)d_in[1];
    const float* b1  = (const float*)d_in[2];
    const float* w2  = (const float*)d_in[3];
    const float* b2  = (const float*)d_in[4];
    const float* fcw = (const float*)d_in[5];
    const float* fcb = (const float*)d_in[6];
    float* out = (float*)d_out;

    fused_cnn<<<512, 512, 0, stream>>>(x, w1, b1, w2, b2, fcw, fcb, out);
}

// Round 6
// 16.692 us; speedup vs baseline: 1.4574x; 1.4574x over previous
//
#include <hip/hip_runtime.h>

// SimpleCNN forward, mathematically simplified (validated rounds 1-4):
//   out = fc( pool(relu(s*conv2+b2)( pool(relu(s*conv1+b1)(x)) )) ),  s = 1/(1+1e-5)
// Round 6: conv2 as implicit-GEMM on MFMA (16x16x32 f16).
//  - h1 stored HWC in LDS: [cg][row 0..17][xcol 0..15][8 ch] f16, zero-padded.
//    B-fragment (8 contiguous k = 8 ch of one tap @ one pixel) = ONE ds_read_b128,
//    bank-group = xcol%8 -> <=2-way (free).
//  - w2 reordered to k=(ki,kj,c), K zero-padded 144->160 (tap 9 x 0 = 0),
//    A-fragments preloaded into 10 h8 registers per lane.
//  - D (32 oc x 196 pix f32) -> LDS scratch stride 197 (group offsets 0,20,8,28:
//    conflict-free), then pool+relu+scale pass -> sh2.
//  - conv1 / fc unchanged from round 4 (256-thread blocks; round 5's 512-thr +
//    shfl-reduce regressed: shuffles are DS-pipe ops, bad trade).

typedef __fp16 h2v __attribute__((ext_vector_type(2)));
typedef __fp16 h8  __attribute__((ext_vector_type(8)));
typedef float  f4  __attribute__((ext_vector_type(4)));

__device__ __forceinline__ unsigned as_u32(h2v h) {
    union { unsigned u; h2v h; } x; x.h = h; return x.u;
}
__device__ __forceinline__ h8 ld_h8(const unsigned* p) {
    union { uint4 u; h8 h; } v; v.u = *(const uint4*)p; return v.h;
}

__global__ __launch_bounds__(256, 2) void fused_cnn(
    const float* __restrict__ x,     // (512,1,28,28)
    const float* __restrict__ w1,    // (16,1,3,3)
    const float* __restrict__ b1,    // (16,)
    const float* __restrict__ w2,    // (32,16,3,3)
    const float* __restrict__ b2,    // (32,)
    const float* __restrict__ fcw,   // (10,1568)
    const float* __restrict__ fcb,   // (10,)
    float* __restrict__ out)         // (512,10)
{
    const int n = blockIdx.x;
    const int t = threadIdx.x;
    const float s = (float)(1.0 / 1.00001);   // 1/(1+TEMP)

    __shared__ float    sx[30 * 36];       // padded x, stride 36, real [1..28][1..28]
    __shared__ unsigned sh1[2 * 18 * 16 * 4]; // h1 HWC f16: [cg][row][xcol][4 u32]
    __shared__ unsigned swr[32 * 80];      // w2 reordered: [oc][80 u32] = 160 f16 (K-pad)
    __shared__ float    Dl[32 * 197];      // conv2 pre-pool output scratch
    __shared__ float    sh2[1568];         // (32,7,7)
    __shared__ float    sred[10][4];

    // ---- stage ----
    for (int i = t; i < 1080; i += 256) sx[i] = 0.0f;
    for (int i = t; i < 2304; i += 256) sh1[i] = 0u;
    if (t < 196) {
        const float4 v = ((const float4*)(x + n * 784))[t];
        const int r = t / 7, c4 = (t - r * 7) * 4;
        float* dst = &sx[(r + 1) * 36 + c4 + 1];
        dst[0] = v.x; dst[1] = v.y; dst[2] = v.z; dst[3] = v.w;
    }
    for (int i = t; i < 2560; i += 256) {            // build swr (k=(ki,kj,c), pad K)
        const int oc = i / 80, r = i - oc * 80;
        unsigned val = 0u;
        if (r < 72) {
            const int ki = r / 24, r2 = r - ki * 24, kj = r2 >> 3, c = 2 * (r2 & 7);
            const float a = w2[(oc * 16 + c) * 9 + ki * 3 + kj];
            const float b = w2[(oc * 16 + c + 1) * 9 + ki * 3 + kj];
            val = as_u32(__builtin_amdgcn_cvt_pkrtz(a, b));
        }
        swr[i] = val;
    }
    __syncthreads();

    // ---- conv1 + relu + pool -> sh1 (HWC packed ch-pairs) ----
    {
        const int ocp = t & 7;                 // out-ch pair (2ocp, 2ocp+1)
        float wa[9], wb[9];
        #pragma unroll
        for (int k = 0; k < 9; ++k) { wa[k] = w1[ocp * 18 + k]; wb[k] = w1[ocp * 18 + 9 + k]; }
        const float ba = b1[2 * ocp], bb = b1[2 * ocp + 1];
        const int cg = ocp >> 2, slot = ocp & 3;

        for (int p = t >> 3; p < 98; p += 32) {
            const int row = p / 7;
            const int pcp = p - row * 7;
            float pr[4][6];
            const float* base = &sx[(2 * row) * 36 + 4 * pcp];
            #pragma unroll
            for (int rr = 0; rr < 4; ++rr) {
                const float4 a4 = *(const float4*)(base + rr * 36);
                const float2 a2 = *(const float2*)(base + rr * 36 + 4);
                pr[rr][0] = a4.x; pr[rr][1] = a4.y; pr[rr][2] = a4.z; pr[rr][3] = a4.w;
                pr[rr][4] = a2.x; pr[rr][5] = a2.y;
            }
            float va[2][4], vb[2][4];
            #pragma unroll
            for (int cr = 0; cr < 2; ++cr)
                #pragma unroll
                for (int cc = 0; cc < 4; ++cc) {
                    float a = 0.0f, b = 0.0f;
                    #pragma unroll
                    for (int ki = 0; ki < 3; ++ki)
                        #pragma unroll
                        for (int kj = 0; kj < 3; ++kj) {
                            const float pv = pr[cr + ki][cc + kj];
                            a = fmaf(wa[ki * 3 + kj], pv, a);
                            b = fmaf(wb[ki * 3 + kj], pv, b);
                        }
                    va[cr][cc] = a; vb[cr][cc] = b;
                }
            #pragma unroll
            for (int d = 0; d < 2; ++d) {
                const float ma = fmaxf(fmaxf(va[0][2 * d], va[0][2 * d + 1]),
                                       fmaxf(va[1][2 * d], va[1][2 * d + 1]));
                const float mb = fmaxf(fmaxf(vb[0][2 * d], vb[0][2 * d + 1]),
                                       fmaxf(vb[1][2 * d], vb[1][2 * d + 1]));
                const float pa = fmaxf(fmaf(s, ma, ba), 0.0f);
                const float pb = fmaxf(fmaf(s, mb, bb), 0.0f);
                const int xc = 2 * pcp + d + 1;         // padded col
                sh1[((cg * 18 + row + 1) * 16 + xc) * 4 + slot] =
                    as_u32(__builtin_amdgcn_cvt_pkrtz(pa, pb));
            }
        }
    }
    __syncthreads();

    // ---- conv2 as implicit GEMM: D[32 oc][196 pix] = W[32][160] * P[160][pix] ----
    {
        const int lane = t & 63, wv = t >> 6;
        const int l15 = lane & 15, kgrp = lane >> 4;
        // A-fragments: lane holds W[oc = m*16 + l15][k = 32s + 8*kgrp .. +8]
        h8 afr[2][5];
        #pragma unroll
        for (int m = 0; m < 2; ++m)
            #pragma unroll
            for (int ss = 0; ss < 5; ++ss)
                afr[m][ss] = ld_h8(&swr[(m * 16 + l15) * 80 + 16 * ss + 4 * kgrp]);

        const int khi = kgrp >> 1, cgl = kgrp & 1;   // tap-offset, ch-granule
        for (int nt = wv; nt < 13; nt += 4) {        // N-tiles of 16 pixels
            const int p = 16 * nt + l15;             // pixel (col); >=196 = padding
            const int y = p / 14, x2 = p - 14 * y;
            h8 bfr[5];
            #pragma unroll
            for (int ss = 0; ss < 5; ++ss) {
                const int tt = 2 * ss + khi;         // tap 0..9 (9 = K-pad, A=0)
                const int ki = tt / 3, kj = tt - 3 * ki;
                const int g = (cgl * 18 + y + ki) * 16 + (x2 + kj);  // 16B granule
                bfr[ss] = ld_h8(&sh1[g * 4]);
            }
            f4 d0 = {0.f, 0.f, 0.f, 0.f}, d1 = {0.f, 0.f, 0.f, 0.f};
            #pragma unroll
            for (int ss = 0; ss < 5; ++ss) {
                d0 = __builtin_amdgcn_mfma_f32_16x16x32_f16(afr[0][ss], bfr[ss], d0, 0, 0, 0);
                d1 = __builtin_amdgcn_mfma_f32_16x16x32_f16(afr[1][ss], bfr[ss], d1, 0, 0, 0);
            }
            if (p < 196) {
                #pragma unroll
                for (int r = 0; r < 4; ++r) {        // D row = oc = m*16 + kgrp*4 + r
                    Dl[(kgrp * 4 + r) * 197 + p]      = d0[r];
                    Dl[(16 + kgrp * 4 + r) * 197 + p] = d1[r];
                }
            }
        }
    }
    __syncthreads();

    // ---- pool + relu + scale -> sh2 ----
    for (int item = t; item < 1568; item += 256) {
        const int oc = item / 49, q = item - oc * 49;
        const int py = q / 7, px = q - py * 7;
        const float* dp = &Dl[oc * 197 + 28 * py + 2 * px];
        const float m = fmaxf(fmaxf(dp[0], dp[1]), fmaxf(dp[14], dp[15]));
        sh2[item] = fmaxf(fmaf(s, m, b2[oc]), 0.0f);
    }
    __syncthreads();

    // ---- fc (float4 vectorized) ----
    float part[10];
    #pragma unroll
    for (int j = 0; j < 10; ++j) part[j] = 0.0f;
    const float4* sh2v = (const float4*)sh2;
    const float4* fcwv = (const float4*)fcw;
    for (int i = t; i < 392; i += 256) {
        const float4 h = sh2v[i];
        #pragma unroll
        for (int j = 0; j < 10; ++j) {
            const float4 wq = fcwv[j * 392 + i];
            part[j] = fmaf(h.x, wq.x, fmaf(h.y, wq.y,
                      fmaf(h.z, wq.z, fmaf(h.w, wq.w, part[j]))));
        }
    }
    #pragma unroll
    for (int j = 0; j < 10; ++j) {
        float vsum = part[j];
        #pragma unroll
        for (int off = 32; off > 0; off >>= 1) vsum += __shfl_down(vsum, off);
        if ((t & 63) == 0) sred[j][t >> 6] = vsum;
    }
    __syncthreads();
    if (t < 10)
        out[n * 10 + t] = sred[t][0] + sred[t][1] + sred[t][2] + sred[t][3] + fcb[t];
}

extern "C" void kernel_launch(void* const* d_in, const int* in_sizes, int n_in,
                              void* d_out, int out_size, void* d_ws, size_t ws_size,
                              hipStream_t stream) {
    const float* x   = (const float*)d_in[0];
    const float* w1  = (const float*)d_in[1];
    const float* b1  = (const float*)d_in[2];
    const float* w2  = (const float*)d_in[3];
    const float* b2  = (const float*)d_in[4];
    const float* fcw = (const float*)d_in[5];
    const float* fcb = (const float*)d_in[6];
    float* out = (float*)d_out;

    fused_cnn<<<512, 256, 0, stream>>>(x, w1, b1, w2, b2, fcw, fcb, out);
}

// Round 7
// 16.277 us; speedup vs baseline: 1.4945x; 1.0255x over previous
//
#include <hip/hip_runtime.h>

// SimpleCNN forward, mathematically simplified (validated rounds 1-6):
//   out = fc( pool(relu(s*conv2+b2)( pool(relu(s*conv1+b1)(x)) )) ),  s = 1/(1+1e-5)
// Round 7: coalesced w2 staging.
//  - w2 loaded as uint4 (coalesced) into raw LDS buffer aliased with Dl (union:
//    [sx | raw_w2] dead before conv2 writes Dl); reorder+f16-pack done LDS->LDS
//    in the conv1 phase (reuses existing barrier). Removes 4608 scalar global
//    loads per block from the critical path.
//  - conv2 = implicit-GEMM on mfma_f32_16x16x32_f16, HWC h1 layout (round 6).

typedef __fp16 h2v __attribute__((ext_vector_type(2)));
typedef __fp16 h8  __attribute__((ext_vector_type(8)));
typedef float  f4  __attribute__((ext_vector_type(4)));

__device__ __forceinline__ unsigned as_u32(h2v h) {
    union { unsigned u; h2v h; } x; x.h = h; return x.u;
}
__device__ __forceinline__ h8 ld_h8(const unsigned* p) {
    union { uint4 u; h8 h; } v; v.u = *(const uint4*)p; return v.h;
}

__global__ __launch_bounds__(256, 2) void fused_cnn(
    const float* __restrict__ x,     // (512,1,28,28)
    const float* __restrict__ w1,    // (16,1,3,3)
    const float* __restrict__ b1,    // (16,)
    const float* __restrict__ w2,    // (32,16,3,3)
    const float* __restrict__ b2,    // (32,)
    const float* __restrict__ fcw,   // (10,1568)
    const float* __restrict__ fcb,   // (10,)
    float* __restrict__ out)         // (512,10)
{
    const int n = blockIdx.x;
    const int t = threadIdx.x;
    const float s = (float)(1.0 / 1.00001);   // 1/(1+TEMP)

    // union region: phase0/1 = [sx 1080 f32 | raw w2 4608 u32], phase2+ = Dl 32x197 f32
    __shared__ float    uni[32 * 197];
    __shared__ unsigned sh1[2 * 18 * 16 * 4];  // h1 HWC f16: [cg][row][xcol][4 u32]
    __shared__ unsigned swr[32 * 80];          // w2 reordered: [oc][80 u32] (K-pad 160)
    __shared__ float    sh2[1568];             // (32,7,7)
    __shared__ float    sred[10][4];

    float*    sx  = uni;                       // 1080 floats
    unsigned* raw = (unsigned*)(uni + 1080);   // 4608 u32 (16B-aligned: 4320B offset)
    float*    Dl  = uni;                       // 32*197 floats (conv2 phase)

    // ---- phase 0: stage ----
    for (int i = t; i < 1080; i += 256) sx[i] = 0.0f;
    for (int i = t; i < 2304; i += 256) sh1[i] = 0u;
    if (t < 196) {
        const float4 v = ((const float4*)(x + n * 784))[t];
        const int r = t / 7, c4 = (t - r * 7) * 4;
        float* dst = &sx[(r + 1) * 36 + c4 + 1];
        dst[0] = v.x; dst[1] = v.y; dst[2] = v.z; dst[3] = v.w;
    }
    {   // coalesced raw w2 copy: 1152 uint4
        uint4* rawv = (uint4*)raw;
        const uint4* w2v = (const uint4*)w2;
        for (int i = t; i < 1152; i += 256) rawv[i] = w2v[i];
    }
    if (t < 256) {  // zero swr K-pad tail (entries 72..79 per oc)
        const int oc = t >> 3;
        swr[oc * 80 + 72 + (t & 7)] = 0u;
    }
    __syncthreads();

    // ---- phase 1: swr convert (LDS->LDS) + conv1 ----
    for (int i = t; i < 2304; i += 256) {      // build swr (k=(ki,kj,c))
        const int oc = i / 72, r = i - oc * 72;
        const int ki = r / 24, r2 = r - ki * 24, kj = r2 >> 3, c = 2 * (r2 & 7);
        const float a = __uint_as_float(raw[(oc * 16 + c) * 9 + ki * 3 + kj]);
        const float b = __uint_as_float(raw[(oc * 16 + c + 1) * 9 + ki * 3 + kj]);
        swr[oc * 80 + r] = as_u32(__builtin_amdgcn_cvt_pkrtz(a, b));
    }
    {
        const int ocp = t & 7;                 // out-ch pair (2ocp, 2ocp+1)
        float wa[9], wb[9];
        #pragma unroll
        for (int k = 0; k < 9; ++k) { wa[k] = w1[ocp * 18 + k]; wb[k] = w1[ocp * 18 + 9 + k]; }
        const float ba = b1[2 * ocp], bb = b1[2 * ocp + 1];
        const int cg = ocp >> 2, slot = ocp & 3;

        for (int p = t >> 3; p < 98; p += 32) {
            const int row = p / 7;
            const int pcp = p - row * 7;
            float pr[4][6];
            const float* base = &sx[(2 * row) * 36 + 4 * pcp];
            #pragma unroll
            for (int rr = 0; rr < 4; ++rr) {
                const float4 a4 = *(const float4*)(base + rr * 36);
                const float2 a2 = *(const float2*)(base + rr * 36 + 4);
                pr[rr][0] = a4.x; pr[rr][1] = a4.y; pr[rr][2] = a4.z; pr[rr][3] = a4.w;
                pr[rr][4] = a2.x; pr[rr][5] = a2.y;
            }
            float va[2][4], vb[2][4];
            #pragma unroll
            for (int cr = 0; cr < 2; ++cr)
                #pragma unroll
                for (int cc = 0; cc < 4; ++cc) {
                    float a = 0.0f, b = 0.0f;
                    #pragma unroll
                    for (int ki = 0; ki < 3; ++ki)
                        #pragma unroll
                        for (int kj = 0; kj < 3; ++kj) {
                            const float pv = pr[cr + ki][cc + kj];
                            a = fmaf(wa[ki * 3 + kj], pv, a);
                            b = fmaf(wb[ki * 3 + kj], pv, b);
                        }
                    va[cr][cc] = a; vb[cr][cc] = b;
                }
            #pragma unroll
            for (int d = 0; d < 2; ++d) {
                const float ma = fmaxf(fmaxf(va[0][2 * d], va[0][2 * d + 1]),
                                       fmaxf(va[1][2 * d], va[1][2 * d + 1]));
                const float mb = fmaxf(fmaxf(vb[0][2 * d], vb[0][2 * d + 1]),
                                       fmaxf(vb[1][2 * d], vb[1][2 * d + 1]));
                const float pa = fmaxf(fmaf(s, ma, ba), 0.0f);
                const float pb = fmaxf(fmaf(s, mb, bb), 0.0f);
                const int xc = 2 * pcp + d + 1;         // padded col
                sh1[((cg * 18 + row + 1) * 16 + xc) * 4 + slot] =
                    as_u32(__builtin_amdgcn_cvt_pkrtz(pa, pb));
            }
        }
    }
    __syncthreads();

    // ---- phase 2: conv2 implicit GEMM: D[32 oc][196 pix] = W[32][160] * P[160][pix] ----
    {
        const int lane = t & 63, wv = t >> 6;
        const int l15 = lane & 15, kgrp = lane >> 4;
        // A-fragments: lane holds W[oc = m*16 + l15][k = 32s + 8*kgrp .. +8]
        h8 afr[2][5];
        #pragma unroll
        for (int m = 0; m < 2; ++m)
            #pragma unroll
            for (int ss = 0; ss < 5; ++ss)
                afr[m][ss] = ld_h8(&swr[(m * 16 + l15) * 80 + 16 * ss + 4 * kgrp]);

        const int khi = kgrp >> 1, cgl = kgrp & 1;   // tap-offset, ch-granule
        for (int nt = wv; nt < 13; nt += 4) {        // N-tiles of 16 pixels
            const int p = 16 * nt + l15;             // pixel (col); >=196 = padding
            const int y = p / 14, x2 = p - 14 * y;
            h8 bfr[5];
            #pragma unroll
            for (int ss = 0; ss < 5; ++ss) {
                const int tt = 2 * ss + khi;         // tap 0..9 (9 = K-pad, A=0)
                const int ki = tt / 3, kj = tt - 3 * ki;
                const int g = (cgl * 18 + y + ki) * 16 + (x2 + kj);  // 16B granule
                bfr[ss] = ld_h8(&sh1[g * 4]);
            }
            f4 d0 = {0.f, 0.f, 0.f, 0.f}, d1 = {0.f, 0.f, 0.f, 0.f};
            #pragma unroll
            for (int ss = 0; ss < 5; ++ss) {
                d0 = __builtin_amdgcn_mfma_f32_16x16x32_f16(afr[0][ss], bfr[ss], d0, 0, 0, 0);
                d1 = __builtin_amdgcn_mfma_f32_16x16x32_f16(afr[1][ss], bfr[ss], d1, 0, 0, 0);
            }
            if (p < 196) {
                #pragma unroll
                for (int r = 0; r < 4; ++r) {        // D row = oc = m*16 + kgrp*4 + r
                    Dl[(kgrp * 4 + r) * 197 + p]      = d0[r];
                    Dl[(16 + kgrp * 4 + r) * 197 + p] = d1[r];
                }
            }
        }
    }
    __syncthreads();

    // ---- phase 3: pool + relu + scale -> sh2 ----
    for (int item = t; item < 1568; item += 256) {
        const int oc = item / 49, q = item - oc * 49;
        const int py = q / 7, px = q - py * 7;
        const float* dp = &Dl[oc * 197 + 28 * py + 2 * px];
        const float m = fmaxf(fmaxf(dp[0], dp[1]), fmaxf(dp[14], dp[15]));
        sh2[item] = fmaxf(fmaf(s, m, b2[oc]), 0.0f);
    }
    __syncthreads();

    // ---- phase 4: fc (float4 vectorized) ----
    float part[10];
    #pragma unroll
    for (int j = 0; j < 10; ++j) part[j] = 0.0f;
    const float4* sh2v = (const float4*)sh2;
    const float4* fcwv = (const float4*)fcw;
    for (int i = t; i < 392; i += 256) {
        const float4 h = sh2v[i];
        #pragma unroll
        for (int j = 0; j < 10; ++j) {
            const float4 wq = fcwv[j * 392 + i];
            part[j] = fmaf(h.x, wq.x, fmaf(h.y, wq.y,
                      fmaf(h.z, wq.z, fmaf(h.w, wq.w, part[j]))));
        }
    }
    #pragma unroll
    for (int j = 0; j < 10; ++j) {
        float vsum = part[j];
        #pragma unroll
        for (int off = 32; off > 0; off >>= 1) vsum += __shfl_down(vsum, off);
        if ((t & 63) == 0) sred[j][t >> 6] = vsum;
    }
    __syncthreads();
    if (t < 10)
        out[n * 10 + t] = sred[t][0] + sred[t][1] + sred[t][2] + sred[t][3] + fcb[t];
}

extern "C" void kernel_launch(void* const* d_in, const int* in_sizes, int n_in,
                              void* d_out, int out_size, void* d_ws, size_t ws_size,
                              hipStream_t stream) {
    const float* x   = (const float*)d_in[0];
    const float* w1  = (const float*)d_in[1];
    const float* b1  = (const float*)d_in[2];
    const float* w2  = (const float*)d_in[3];
    const float* b2  = (const float*)d_in[4];
    const float* fcw = (const float*)d_in[5];
    const float* fcb = (const float*)d_in[6];
    float* out = (float*)d_out;

    fused_cnn<<<512, 256, 0, stream>>>(x, w1, b1, w2, b2, fcw, fcb, out);
}